// Round 1
// baseline (252.933 us; speedup 1.0000x reference)
//
#include <hip/hip_runtime.h>
#include <math.h>

#define N_EXC   20000
#define N_KCC   1024
#define FDIM    128
#define LEAKY_S 0.2f

#define BR  32      // exercise rows per block
#define TJ  64      // kc (j) tile
#define EXS 129     // ex_lds / eh_lds stride (conflict-free column reads)
#define WST 36      // w_lds stride (16B-aligned b128 reads, 2-way-free writes)

// ws float layout:
// [0]                    kcWh   N_KCC*FDIM   (512 KB)
// [N_KCC*FDIM]           t      N_KCC
// [N_KCC*FDIM + N_KCC]   w1a1   FDIM

__global__ __launch_bounds__(128) void gat_prep(const float* __restrict__ kc_h,
                                                const float* __restrict__ W1,
                                                const float* __restrict__ a,
                                                float* __restrict__ ws)
{
    float* kcWh = ws;
    float* tarr = ws + N_KCC * FDIM;
    float* w1a1 = tarr + N_KCC;
    const int tid = threadIdx.x;
    const int j = blockIdx.x;

    if (j == N_KCC) {
        // w1a1[k] = sum_f W1[k][f] * a1[f]
        float acc = 0.f;
        const float* row = W1 + tid * FDIM;
        #pragma unroll 8
        for (int f = 0; f < FDIM; ++f) acc += row[f] * a[f];
        w1a1[tid] = acc;
        return;
    }

    __shared__ float kcrow[FDIM];
    __shared__ float red[FDIM];
    kcrow[tid] = kc_h[j * FDIM + tid];
    __syncthreads();
    float acc = 0.f;
    #pragma unroll 8
    for (int k = 0; k < FDIM; ++k) acc += kcrow[k] * W1[k * FDIM + tid];
    kcWh[j * FDIM + tid] = acc;
    // t[j] = sum_f kcWh[j][f] * a2[f]
    red[tid] = acc * a[FDIM + tid];
    __syncthreads();
    for (int s = 64; s > 0; s >>= 1) {
        if (tid < s) red[tid] += red[tid + s];
        __syncthreads();
    }
    if (tid == 0) tarr[j] = red[0];
}

__global__ __launch_bounds__(256) void gat_main(const float* __restrict__ ex_h,
                                                const int* __restrict__ adj,
                                                const float* __restrict__ E,
                                                const float* __restrict__ ws,
                                                float* __restrict__ out)
{
    const float* kcWh = ws;
    const float* tarr = ws + N_KCC * FDIM;
    const float* w1a1 = tarr + N_KCC;

    __shared__ float t_lds[N_KCC];        // 4 KB
    __shared__ float ex_lds[BR * EXS];    // 16.5 KB
    __shared__ float kc_lds[TJ * FDIM];   // 32 KB (also E staging)
    __shared__ float w_lds[TJ * WST];     // 9 KB
    __shared__ float eh_lds[BR * EXS];    // 16.5 KB
    __shared__ float w1a1_lds[FDIM];
    __shared__ float s_lds[BR];
    __shared__ float m_lds[BR];
    __shared__ float denom_lds[BR];
    __shared__ float scratch[256];
    __shared__ float Tmax_lds;

    const int tid = threadIdx.x;
    const int R0 = blockIdx.x * BR;

    // ---- phase 0: stage t, w1a1, ex rows ----
    #pragma unroll
    for (int u = 0; u < 4; ++u) t_lds[u * 256 + tid] = tarr[u * 256 + tid];
    if (tid < FDIM) w1a1_lds[tid] = w1a1[tid];
    #pragma unroll
    for (int u = 0; u < 4; ++u) {
        int flat = (u * 256 + tid) * 4;
        int r = flat >> 7, f = flat & 127;
        float4 v = *(const float4*)(ex_h + (size_t)(R0 + r) * FDIM + f);
        ex_lds[r * EXS + f + 0] = v.x;
        ex_lds[r * EXS + f + 1] = v.y;
        ex_lds[r * EXS + f + 2] = v.z;
        ex_lds[r * EXS + f + 3] = v.w;
    }
    __syncthreads();

    // ---- T = max_j t_j (block-local reduce; every block computes it) ----
    {
        float mx = t_lds[tid];
        mx = fmaxf(mx, t_lds[256 + tid]);
        mx = fmaxf(mx, t_lds[512 + tid]);
        mx = fmaxf(mx, t_lds[768 + tid]);
        scratch[tid] = mx;
    }
    __syncthreads();
    if (tid < 64) {
        scratch[tid] = fmaxf(fmaxf(scratch[tid], scratch[tid + 64]),
                             fmaxf(scratch[tid + 128], scratch[tid + 192]));
    }
    __syncthreads();
    if (tid == 0) {
        float mx = scratch[0];
        for (int i = 1; i < 64; ++i) mx = fmaxf(mx, scratch[i]);
        Tmax_lds = mx;
    }
    __syncthreads();

    // ---- s_r = ex_row . w1a1 ; m_r = leaky(s_r + T) ----
    {
        int r = tid & 31, kg = tid >> 5;
        float p = 0.f;
        #pragma unroll
        for (int i = 0; i < 16; ++i)
            p += ex_lds[r * EXS + kg * 16 + i] * w1a1_lds[kg * 16 + i];
        scratch[kg * 32 + r] = p;
    }
    __syncthreads();
    if (tid < BR) {
        float s = 0.f;
        #pragma unroll
        for (int g = 0; g < 8; ++g) s += scratch[g * 32 + tid];
        s_lds[tid] = s;
        float x = s + Tmax_lds;
        m_lds[tid] = (x >= 0.f) ? x : LEAKY_S * x;
    }
    __syncthreads();

    // ---- Eh = ex @ E -> eh_lds (E streamed through kc_lds in 2 halves) ----
    {
        const int r = tid & 31, fg = tid >> 5;
        float acc[16];
        #pragma unroll
        for (int i = 0; i < 16; ++i) acc[i] = 0.f;
        for (int p = 0; p < 2; ++p) {
            __syncthreads();
            #pragma unroll
            for (int u = 0; u < 8; ++u) {
                int flat = (u * 256 + tid) * 4;
                *(float4*)(kc_lds + flat) = *(const float4*)(E + p * 64 * FDIM + flat);
            }
            __syncthreads();
            for (int k = 0; k < 64; ++k) {
                float ev = ex_lds[r * EXS + p * 64 + k];
                const float* Er = kc_lds + k * FDIM + fg * 16;
                #pragma unroll
                for (int i = 0; i < 16; ++i) acc[i] += ev * Er[i];
            }
        }
        #pragma unroll
        for (int i = 0; i < 16; ++i) eh_lds[r * EXS + fg * 16 + i] = acc[i];
        // no sync needed here: j-loop opens with __syncthreads()
    }

    // ---- main j loop: single-pass masked softmax numerator GEMM ----
    const int r_w = tid & 31;   // row this thread generates w for
    const int jg  = tid >> 5;   // 8-j group
    const int ty  = tid >> 5;   // GEMM row group (rows ty*4..+3)
    const int tx  = tid & 31;   // GEMM col group (cols tx*4..+3)
    const float sr = s_lds[r_w];
    const float mr = m_lds[r_w];
    float denom_part = 0.f;
    float acc[4][4];
    #pragma unroll
    for (int i = 0; i < 4; ++i)
        #pragma unroll
        for (int c = 0; c < 4; ++c) acc[i][c] = 0.f;

    for (int jt = 0; jt < N_KCC / TJ; ++jt) {
        const int j0 = jt * TJ;
        __syncthreads();   // prev GEMM reads done before restaging
        // stage kc_Wh tile
        #pragma unroll
        for (int u = 0; u < 8; ++u) {
            int flat = (u * 256 + tid) * 4;
            *(float4*)(kc_lds + flat) = *(const float4*)(kcWh + j0 * FDIM + flat);
        }
        // w generation: thread -> (row r_w, 8 consecutive j)
        {
            const int jb = j0 + jg * 8;
            const int* ap = adj + (size_t)(R0 + r_w) * N_KCC + jb;
            int4 a0  = *(const int4*)(ap);
            int4 a1v = *(const int4*)(ap + 4);
            int av[8] = {a0.x, a0.y, a0.z, a0.w, a1v.x, a1v.y, a1v.z, a1v.w};
            #pragma unroll
            for (int i = 0; i < 8; ++i) {
                float x = sr + t_lds[jb + i];
                x = (x >= 0.f) ? x : LEAKY_S * x;
                float w = __expf(x - mr);
                w = (av[i] > 0) ? w : 0.f;
                denom_part += w;
                w_lds[(jg * 8 + i) * WST + r_w] = w;
            }
        }
        __syncthreads();
        // register-tiled GEMM: acc[4][4] += w[32][64-tile]^ * kc[64][128]
        #pragma unroll 8
        for (int k = 0; k < TJ; ++k) {
            float4 av4 = *(const float4*)(w_lds + k * WST + ty * 4);
            float4 bv4 = *(const float4*)(kc_lds + k * FDIM + tx * 4);
            float a4[4] = {av4.x, av4.y, av4.z, av4.w};
            float b4[4] = {bv4.x, bv4.y, bv4.z, bv4.w};
            #pragma unroll
            for (int i = 0; i < 4; ++i)
                #pragma unroll
                for (int c = 0; c < 4; ++c)
                    acc[i][c] += a4[i] * b4[c];
        }
    }

    // ---- denominator reduce ----
    __syncthreads();
    scratch[jg * 32 + r_w] = denom_part;
    __syncthreads();
    if (tid < BR) {
        float d = 0.f;
        #pragma unroll
        for (int g = 0; g < 8; ++g) d += scratch[g * 32 + tid];
        denom_lds[tid] = (d > 0.f) ? d : 1.f;  // all-masked row: unreachable for this data
    }
    __syncthreads();

    // ---- epilogue: normalize, * Eh, elu, store ----
    #pragma unroll
    for (int i = 0; i < 4; ++i) {
        int row = ty * 4 + i;
        float rd = 1.f / denom_lds[row];
        float vv[4];
        #pragma unroll
        for (int c = 0; c < 4; ++c) {
            float avg = acc[i][c] * rd;
            float eh = eh_lds[row * EXS + tx * 4 + c];
            float v = avg * eh;
            vv[c] = (v > 0.f) ? v : expm1f(v);
        }
        float4 o = {vv[0], vv[1], vv[2], vv[3]};
        *(float4*)(out + (size_t)(R0 + row) * FDIM + tx * 4) = o;
    }
}

extern "C" void kernel_launch(void* const* d_in, const int* in_sizes, int n_in,
                              void* d_out, int out_size, void* d_ws, size_t ws_size,
                              hipStream_t stream)
{
    const float* ex_h = (const float*)d_in[0];
    const float* kc_h = (const float*)d_in[1];
    const int*   adj  = (const int*)d_in[2];
    const float* W1   = (const float*)d_in[3];
    const float* E    = (const float*)d_in[4];
    const float* a    = (const float*)d_in[5];
    float* outp = (float*)d_out;
    float* ws   = (float*)d_ws;

    gat_prep<<<N_KCC + 1, 128, 0, stream>>>(kc_h, W1, a, ws);
    gat_main<<<N_EXC / BR, 256, 0, stream>>>(ex_h, adj, E, ws, outp);
}

// Round 2
// 164.191 us; speedup vs baseline: 1.5405x; 1.5405x over previous
//
#include <hip/hip_runtime.h>
#include <math.h>

#define N_EXC   20000
#define N_KCC   1024
#define FDIM    128
#define LEAKY_S 0.2f

#define BR  32      // exercise rows per block
#define TJ  64      // kc (j) tile
#define EXS 136     // ex_lds stride in ushorts (272 B, 16B-aligned, bank-even for b128)
#define KCS 72      // kc_lds / w_lds stride in ushorts (144 B, 16B-aligned, bank-even)

typedef __attribute__((ext_vector_type(8))) short short8;
typedef __attribute__((ext_vector_type(4))) float floatx4;

__device__ __forceinline__ unsigned short f2bf(float f) {
    unsigned u = __float_as_uint(f);
    u += 0x7FFF + ((u >> 16) & 1);          // RNE
    return (unsigned short)(u >> 16);
}

// ws layout (bytes):
//   [0)        tarr   : 1024 f32   (4096 B)
//   [4096)     w1a1   : 128 f32    (512 B)
//   [4608)     kcWh_t : 128x1024 bf16 (262144 B)   kcWh_t[f][j]
//   [266752)   E_t    : 128x128 bf16  (32768 B)    E_t[n][k]

__global__ __launch_bounds__(256) void gat_prep(const float* __restrict__ kc_h,
                                                const float* __restrict__ W1,
                                                const float* __restrict__ E,
                                                const float* __restrict__ a,
                                                float* __restrict__ ws)
{
    float* tarr = ws;
    float* w1a1 = ws + N_KCC;
    unsigned short* kcWh_t = (unsigned short*)(ws + N_KCC + FDIM);
    unsigned short* E_t    = kcWh_t + FDIM * N_KCC;
    const int tid = threadIdx.x;
    const int b = blockIdx.x;

    if (b == 128) {                       // w1a1[k] = W1[k][:] . a1
        if (tid < FDIM) {
            float acc = 0.f;
            const float* row = W1 + tid * FDIM;
            #pragma unroll 8
            for (int f = 0; f < FDIM; ++f) acc += row[f] * a[f];
            w1a1[tid] = acc;
        }
        return;
    }
    if (b == 129) {                       // E_t[n][k] = bf16(E[k][n])
        for (int u = 0; u < 64; ++u) {
            int flat = u * 256 + tid;
            int k = flat >> 7, n = flat & 127;
            E_t[n * FDIM + k] = f2bf(E[flat]);
        }
        return;
    }

    // blocks 0..127: 8 kc rows each. kcWh[j][f] fp32 in regs -> bf16 transpose + t[j]
    __shared__ float kcr[8 * FDIM];
    __shared__ float red[256];
    #pragma unroll
    for (int u = 0; u < 4; ++u) {
        int flat = u * 256 + tid;
        kcr[flat] = kc_h[b * 8 * FDIM + flat];
    }
    __syncthreads();
    const int jl = tid >> 5, fg = tid & 31;
    const int j = b * 8 + jl;
    float acc0 = 0.f, acc1 = 0.f, acc2 = 0.f, acc3 = 0.f;
    #pragma unroll 4
    for (int k = 0; k < FDIM; ++k) {
        float kv = kcr[jl * FDIM + k];
        float4 w4 = *(const float4*)(W1 + k * FDIM + fg * 4);
        acc0 += kv * w4.x; acc1 += kv * w4.y; acc2 += kv * w4.z; acc3 += kv * w4.w;
    }
    kcWh_t[(fg * 4 + 0) * N_KCC + j] = f2bf(acc0);
    kcWh_t[(fg * 4 + 1) * N_KCC + j] = f2bf(acc1);
    kcWh_t[(fg * 4 + 2) * N_KCC + j] = f2bf(acc2);
    kcWh_t[(fg * 4 + 3) * N_KCC + j] = f2bf(acc3);
    float p = acc0 * a[FDIM + fg * 4 + 0] + acc1 * a[FDIM + fg * 4 + 1]
            + acc2 * a[FDIM + fg * 4 + 2] + acc3 * a[FDIM + fg * 4 + 3];
    red[tid] = p;
    __syncthreads();
    if (tid < 8) {
        float s = 0.f;
        #pragma unroll 8
        for (int l = 0; l < 32; ++l) s += red[tid * 32 + l];
        tarr[b * 8 + tid] = s;
    }
}

__global__ __launch_bounds__(256, 4) void gat_main(const float* __restrict__ ex_h,
                                                   const int* __restrict__ adj,
                                                   const float* __restrict__ ws,
                                                   float* __restrict__ out)
{
    const float* tarr = ws;
    const float* w1a1 = ws + N_KCC;
    const unsigned short* kcWh_t = (const unsigned short*)(ws + N_KCC + FDIM);
    const unsigned short* E_t    = kcWh_t + FDIM * N_KCC;

    __shared__ float t_lds[N_KCC];                 // 4 KB
    __shared__ unsigned short ex_lds[BR * EXS];    // 8.7 KB  ex rows bf16 [r][f]
    __shared__ unsigned short kc_lds[FDIM * KCS];  // 18.4 KB kc tile / E staging
    __shared__ unsigned short w_lds[BR * KCS];     // 4.6 KB  w tile bf16 [r][j]
    __shared__ float w1a1_lds[FDIM];
    __shared__ float scrA[256];
    __shared__ float scrB[256];
    __shared__ float s_lds[BR], m_lds[BR], denom_lds[BR];

    const int tid  = threadIdx.x;
    const int R0   = blockIdx.x * BR;
    const int lane = tid & 63, wid = tid >> 6;
    const int l15  = lane & 15, quad = lane >> 4;

    // ---- phase 0: stage t, w1a1; load ex rows (f32 regs -> bf16 LDS) ----
    #pragma unroll
    for (int u = 0; u < 4; ++u) t_lds[u * 256 + tid] = tarr[u * 256 + tid];
    if (tid < FDIM) w1a1_lds[tid] = w1a1[tid];
    const int r0 = tid >> 3;
    const int fc = (tid & 7) * 16;
    float exv[16];
    {
        const float* src = ex_h + (size_t)(R0 + r0) * FDIM + fc;
        #pragma unroll
        for (int c = 0; c < 4; ++c) {
            float4 v = *(const float4*)(src + c * 4);
            exv[c * 4 + 0] = v.x; exv[c * 4 + 1] = v.y;
            exv[c * 4 + 2] = v.z; exv[c * 4 + 3] = v.w;
        }
        unsigned pk[8];
        #pragma unroll
        for (int i = 0; i < 8; ++i)
            pk[i] = (unsigned)f2bf(exv[2 * i]) | ((unsigned)f2bf(exv[2 * i + 1]) << 16);
        *(uint4*)(ex_lds + r0 * EXS + fc)     = make_uint4(pk[0], pk[1], pk[2], pk[3]);
        *(uint4*)(ex_lds + r0 * EXS + fc + 8) = make_uint4(pk[4], pk[5], pk[6], pk[7]);
    }
    __syncthreads();

    // ---- Tmax partials + s partials (fp32 ex from regs) ----
    {
        float mx = fmaxf(fmaxf(t_lds[tid], t_lds[256 + tid]),
                         fmaxf(t_lds[512 + tid], t_lds[768 + tid]));
        scrB[tid] = mx;
        float p = 0.f;
        #pragma unroll
        for (int i = 0; i < 16; ++i) p += exv[i] * w1a1_lds[fc + i];
        scrA[tid] = p;
    }
    __syncthreads();
    if (tid < 64)
        scrB[tid] = fmaxf(fmaxf(scrB[tid], scrB[tid + 64]),
                          fmaxf(scrB[tid + 128], scrB[tid + 192]));
    __syncthreads();
    if (tid < BR) {
        float Tm = scrB[0];
        #pragma unroll 8
        for (int i = 1; i < 64; ++i) Tm = fmaxf(Tm, scrB[i]);
        float s = 0.f;
        #pragma unroll
        for (int g = 0; g < 8; ++g) s += scrA[tid * 8 + g];
        s_lds[tid] = s;
        float x = s + Tm;
        m_lds[tid] = (x >= 0.f) ? x : LEAKY_S * x;
    }
    // (barriers inside the Eh phase below make s/m visible before the j-loop)

    // ---- Eh = ex @ E via MFMA; acc mapping identical to attention acc ----
    floatx4 eh_acc[2][2], att_acc[2][2];
    #pragma unroll
    for (int mg = 0; mg < 2; ++mg)
        #pragma unroll
        for (int h = 0; h < 2; ++h) {
            eh_acc[mg][h] = (floatx4){0.f, 0.f, 0.f, 0.f};
            att_acc[mg][h] = (floatx4){0.f, 0.f, 0.f, 0.f};
        }
    #pragma unroll
    for (int h = 0; h < 2; ++h) {
        __syncthreads();
        // stage E_t rows n = h*64 .. h*64+63 into kc_lds (stride EXS)
        #pragma unroll
        for (int u = 0; u < 4; ++u) {
            int flat = u * 256 + tid;
            int n = flat >> 4, kp = (flat & 15) * 8;
            *(int4*)(kc_lds + n * EXS + kp) = *(const int4*)(E_t + (h * 64 + n) * FDIM + kp);
        }
        __syncthreads();
        #pragma unroll
        for (int kk = 0; kk < 4; ++kk) {
            short8 a0 = *(const short8*)(ex_lds + (l15) * EXS + kk * 32 + quad * 8);
            short8 a1 = *(const short8*)(ex_lds + (16 + l15) * EXS + kk * 32 + quad * 8);
            short8 bf = *(const short8*)(kc_lds + (wid * 16 + l15) * EXS + kk * 32 + quad * 8);
            eh_acc[0][h] = __builtin_amdgcn_mfma_f32_16x16x32_bf16(a0, bf, eh_acc[0][h], 0, 0, 0);
            eh_acc[1][h] = __builtin_amdgcn_mfma_f32_16x16x32_bf16(a1, bf, eh_acc[1][h], 0, 0, 0);
        }
    }

    // ---- main j loop ----
    const int r_w = tid >> 3;         // w-gen row (coalesced adj: 8 lanes per row)
    const int jg  = tid & 7;          // 8-j chunk
    const float sr = s_lds[r_w];
    const float mr = m_lds[r_w];
    float denom_part = 0.f;
    const int* aptr0 = adj + (size_t)(R0 + r_w) * N_KCC + jg * 8;
    int4 nx0 = *(const int4*)(aptr0);
    int4 nx1 = *(const int4*)(aptr0 + 4);

    for (int jt = 0; jt < N_KCC / TJ; ++jt) {
        const int j0 = jt * TJ;
        int4 c0 = nx0, c1 = nx1;
        __syncthreads();                       // prev-tile MFMA reads done
        // stage kc_t tile [128 f][64 j] bf16
        #pragma unroll
        for (int u = 0; u < 4; ++u) {
            int flat = u * 256 + tid;
            int f = flat >> 3, jp = (flat & 7) * 8;
            *(int4*)(kc_lds + f * KCS + jp) = *(const int4*)(kcWh_t + f * N_KCC + j0 + jp);
        }
        // prefetch next tile's adj
        {
            int jn = (jt + 1 < N_KCC / TJ) ? (jt + 1) * TJ : jt * TJ;
            nx0 = *(const int4*)(aptr0 + jn);
            nx1 = *(const int4*)(aptr0 + jn + 4);
        }
        // w generation (fp32), bf16 pack -> w_lds
        {
            const int jb = j0 + jg * 8;
            float4 t4a = *(const float4*)(t_lds + jb);
            float4 t4b = *(const float4*)(t_lds + jb + 4);
            float tv[8] = {t4a.x, t4a.y, t4a.z, t4a.w, t4b.x, t4b.y, t4b.z, t4b.w};
            int   av[8] = {c0.x, c0.y, c0.z, c0.w, c1.x, c1.y, c1.z, c1.w};
            unsigned pk[4];
            #pragma unroll
            for (int i = 0; i < 4; ++i) {
                float w2[2];
                #pragma unroll
                for (int e = 0; e < 2; ++e) {
                    float x = sr + tv[2 * i + e];
                    x = (x >= 0.f) ? x : LEAKY_S * x;
                    float wv = __expf(x - mr);
                    wv = (av[2 * i + e] > 0) ? wv : 0.f;
                    denom_part += wv;
                    w2[e] = wv;
                }
                pk[i] = (unsigned)f2bf(w2[0]) | ((unsigned)f2bf(w2[1]) << 16);
            }
            *(uint4*)(w_lds + r_w * KCS + jg * 8) = make_uint4(pk[0], pk[1], pk[2], pk[3]);
        }
        __syncthreads();
        // MFMA: att_acc[mg][h] += w[32 x 64] @ kc[64 x 128]
        #pragma unroll
        for (int kk = 0; kk < 2; ++kk) {
            short8 a0 = *(const short8*)(w_lds + (l15) * KCS + kk * 32 + quad * 8);
            short8 a1 = *(const short8*)(w_lds + (16 + l15) * KCS + kk * 32 + quad * 8);
            short8 b0 = *(const short8*)(kc_lds + ((wid) * 16 + l15) * KCS + kk * 32 + quad * 8);
            short8 b1 = *(const short8*)(kc_lds + ((4 + wid) * 16 + l15) * KCS + kk * 32 + quad * 8);
            att_acc[0][0] = __builtin_amdgcn_mfma_f32_16x16x32_bf16(a0, b0, att_acc[0][0], 0, 0, 0);
            att_acc[1][0] = __builtin_amdgcn_mfma_f32_16x16x32_bf16(a1, b0, att_acc[1][0], 0, 0, 0);
            att_acc[0][1] = __builtin_amdgcn_mfma_f32_16x16x32_bf16(a0, b1, att_acc[0][1], 0, 0, 0);
            att_acc[1][1] = __builtin_amdgcn_mfma_f32_16x16x32_bf16(a1, b1, att_acc[1][1], 0, 0, 0);
        }
    }

    // ---- denominator reduce ----
    __syncthreads();
    scrA[tid] = denom_part;
    __syncthreads();
    if (tid < BR) {
        float d = 0.f;
        #pragma unroll
        for (int g = 0; g < 8; ++g) d += scrA[tid * 8 + g];
        denom_lds[tid] = (d > 0.f) ? d : 1.f;
    }
    __syncthreads();

    // ---- epilogue: normalize * Eh, elu, store (C-layout: col=l15, row=quad*4+reg) ----
    #pragma unroll
    for (int mg = 0; mg < 2; ++mg) {
        float rd[4];
        #pragma unroll
        for (int reg = 0; reg < 4; ++reg)
            rd[reg] = 1.f / denom_lds[mg * 16 + quad * 4 + reg];
        #pragma unroll
        for (int h = 0; h < 2; ++h) {
            const int col = (h * 4 + wid) * 16 + l15;
            #pragma unroll
            for (int reg = 0; reg < 4; ++reg) {
                const int rl = mg * 16 + quad * 4 + reg;
                float v = att_acc[mg][h][reg] * rd[reg] * eh_acc[mg][h][reg];
                out[(size_t)(R0 + rl) * FDIM + col] = (v > 0.f) ? v : expm1f(v);
            }
        }
    }
}

extern "C" void kernel_launch(void* const* d_in, const int* in_sizes, int n_in,
                              void* d_out, int out_size, void* d_ws, size_t ws_size,
                              hipStream_t stream)
{
    const float* ex_h = (const float*)d_in[0];
    const float* kc_h = (const float*)d_in[1];
    const int*   adj  = (const int*)d_in[2];
    const float* W1   = (const float*)d_in[3];
    const float* E    = (const float*)d_in[4];
    const float* a    = (const float*)d_in[5];
    float* outp = (float*)d_out;
    float* ws   = (float*)d_ws;

    gat_prep<<<130, 256, 0, stream>>>(kc_h, W1, E, a, ws);
    gat_main<<<N_EXC / BR, 256, 0, stream>>>(ex_h, adj, ws, outp);
}

// Round 4
// 157.960 us; speedup vs baseline: 1.6012x; 1.0395x over previous
//
#include <hip/hip_runtime.h>
#include <math.h>

#define N_EXC   20000
#define N_KCC   1024
#define FDIM    128
#define LEAKY_S 0.2f

#define BR  32       // exercise rows per block
#define TJ  128      // kc (j) tile (8 tiles)
#define EXS 136      // ex/w LDS stride in ushorts (272 B: 2-way-free for b128)

typedef unsigned short ushort_t;
typedef __attribute__((ext_vector_type(8))) short short8;
typedef __attribute__((ext_vector_type(4))) float floatx4;

__device__ __forceinline__ ushort_t f2bf(float f) {
    unsigned u = __float_as_uint(f);
    u += 0x7FFF + ((u >> 16) & 1);          // RNE
    return (ushort_t)(u >> 16);
}

// async global->LDS, 16 B per lane. LDS dest must be wave-uniform base + lane*16.
// NOTE: direct cast (addrspacecast), NOT via uintptr_t — the integer round-trip
// reinterprets the flat address instead of converting it to an LDS offset.
__device__ __forceinline__ void async16(const void* g, void* l) {
    __builtin_amdgcn_global_load_lds(
        (const __attribute__((address_space(1))) unsigned int*)g,
        (__attribute__((address_space(3))) unsigned int*)l,
        16, 0, 0);
}

// ws layout (float offsets):
//   [0)     tarr  1024 f32
//   [1024)  w1a1  128 f32
//   [1152)  kc_sw 131072 ushorts (256 KB): 8 tiles x [f=128][c'=16][e=8],
//           c' = (j_loc>>3) ^ (f&15), value = bf16(kcWh[j][f])
//   [+256K) E_sw  16384 ushorts (32 KB): [n=128][c'=16][e=8],
//           c' = (k>>3) ^ (n&15), value = bf16(E[k][n])

__global__ __launch_bounds__(256) void gat_prep(const float* __restrict__ kc_h,
                                                const float* __restrict__ W1,
                                                const float* __restrict__ E,
                                                const float* __restrict__ a,
                                                float* __restrict__ ws)
{
    float* tarr = ws;
    float* w1a1 = ws + N_KCC;
    ushort_t* kc_sw = (ushort_t*)(ws + N_KCC + FDIM);
    ushort_t* E_sw  = kc_sw + FDIM * N_KCC;
    const int tid = threadIdx.x;
    const int b = blockIdx.x;

    __shared__ __align__(16) float kct[128 * 132];     // 67.6 KB
    __shared__ __align__(16) ushort_t sw[32 * 128];    // 8 KB
    __shared__ __align__(16) float w1a2_lds[FDIM];

    if (b < 32) {
        // kcWh tile: j-tile jb (128 rows), f-quarter fq (32 cols)
        const int jb = b >> 2, fq = b & 3;
        const float* kcbase = kc_h + (size_t)jb * 128 * FDIM;
        #pragma unroll
        for (int u = 0; u < 16; ++u) {
            int flat = u * 256 + tid;
            int r = flat >> 5, c4 = (flat & 31) * 4;
            float4 v = *(const float4*)(kcbase + r * FDIM + c4);
            kct[r * 132 + c4 + 0] = v.x; kct[r * 132 + c4 + 1] = v.y;
            kct[r * 132 + c4 + 2] = v.z; kct[r * 132 + c4 + 3] = v.w;
        }
        __syncthreads();
        const int jg = tid >> 4;                 // j rows jg*8..+7
        const int fg = tid & 15;                 // 2 f cols
        const int f0 = fq * 32 + fg * 2;
        float acc[8][2];
        #pragma unroll
        for (int i = 0; i < 8; ++i) { acc[i][0] = 0.f; acc[i][1] = 0.f; }
        for (int k4 = 0; k4 < FDIM; k4 += 4) {
            float4 av[8];
            #pragma unroll
            for (int i = 0; i < 8; ++i)
                av[i] = *(const float4*)(kct + (jg * 8 + i) * 132 + k4);
            #pragma unroll
            for (int kk = 0; kk < 4; ++kk) {
                float2 bv = *(const float2*)(W1 + (k4 + kk) * FDIM + f0);
                #pragma unroll
                for (int i = 0; i < 8; ++i) {
                    float a_ = ((const float*)&av[i])[kk];
                    acc[i][0] += a_ * bv.x;
                    acc[i][1] += a_ * bv.y;
                }
            }
        }
        // pack 8 e per (f) into uint4, swizzled chunk c' = jg ^ (f&15)
        #pragma unroll
        for (int c = 0; c < 2; ++c) {
            int f = f0 + c;
            int fl = fg * 2 + c;
            unsigned pk[4];
            #pragma unroll
            for (int i = 0; i < 4; ++i)
                pk[i] = (unsigned)f2bf(acc[2 * i][c]) | ((unsigned)f2bf(acc[2 * i + 1][c]) << 16);
            int cp = jg ^ (f & 15);
            *(uint4*)(sw + fl * 128 + cp * 8) = make_uint4(pk[0], pk[1], pk[2], pk[3]);
        }
        __syncthreads();
        ushort_t* dst = kc_sw + ((size_t)jb * 128 + fq * 32) * 128;
        #pragma unroll
        for (int u = 0; u < 2; ++u) {
            int flat = u * 256 + tid;
            *(uint4*)(dst + flat * 8) = *(const uint4*)(sw + flat * 8);
        }
        return;
    }

    if (b < 36) {
        // t[j] = kc[j] . (W1 @ a2); block 32 also writes w1a1
        if (tid >= 128) {
            int k = tid - 128;
            float acc = 0.f;
            const float* row = W1 + k * FDIM;
            #pragma unroll 8
            for (int f = 0; f < FDIM; ++f) acc += row[f] * a[FDIM + f];
            w1a2_lds[k] = acc;
        } else if (b == 32) {
            float acc = 0.f;
            const float* row = W1 + tid * FDIM;
            #pragma unroll 8
            for (int f = 0; f < FDIM; ++f) acc += row[f] * a[f];
            w1a1[tid] = acc;
        }
        __syncthreads();
        int j = (b - 32) * 256 + tid;
        float s = 0.f;
        #pragma unroll 8
        for (int c = 0; c < 32; ++c) {
            float4 v = *(const float4*)(kc_h + (size_t)j * FDIM + c * 4);
            s += v.x * w1a2_lds[c * 4 + 0] + v.y * w1a2_lds[c * 4 + 1]
               + v.z * w1a2_lds[c * 4 + 2] + v.w * w1a2_lds[c * 4 + 3];
        }
        tarr[j] = s;
        return;
    }

    // b == 36: E_sw swizzled bf16
    #pragma unroll
    for (int u = 0; u < 8; ++u) {
        int ch = u * 256 + tid;          // 2048 chunks
        int n = ch >> 4, cp = ch & 15;
        int c = cp ^ (n & 15);
        unsigned pk[4];
        #pragma unroll
        for (int i = 0; i < 4; ++i) {
            float e0 = E[(c * 8 + 2 * i + 0) * FDIM + n];
            float e1 = E[(c * 8 + 2 * i + 1) * FDIM + n];
            pk[i] = (unsigned)f2bf(e0) | ((unsigned)f2bf(e1) << 16);
        }
        *(uint4*)(E_sw + ch * 8) = make_uint4(pk[0], pk[1], pk[2], pk[3]);
    }
}

__global__ __launch_bounds__(256, 3) void gat_main(const float* __restrict__ ex_h,
                                                   const int* __restrict__ adj,
                                                   const float* __restrict__ ws,
                                                   float* __restrict__ out)
{
    const float* tarr = ws;
    const float* w1a1 = ws + N_KCC;
    const ushort_t* kc_sw = (const ushort_t*)(ws + N_KCC + FDIM);
    const ushort_t* E_sw  = kc_sw + FDIM * N_KCC;

    __shared__ __align__(16) float t_lds[N_KCC];            // 4 KB
    __shared__ __align__(16) ushort_t kc_lds[FDIM * TJ];    // 32 KB (E, then kc tiles)
    __shared__ __align__(16) ushort_t exw_lds[BR * EXS];    // 8.7 KB (ex, then w)
    __shared__ __align__(16) float scrA[256];
    __shared__ __align__(16) float scrB[256];
    __shared__ float w1a1_lds[FDIM];
    __shared__ float s_lds[BR], m_lds[BR], denom_lds[BR];

    const int tid  = threadIdx.x;
    const int R0   = blockIdx.x * BR;
    const int lane = tid & 63, wid = tid >> 6;
    const int l15  = lane & 15, quad = lane >> 4;

    // ---- issue E async load first (32 KB) ----
    #pragma unroll
    for (int u = 0; u < 8; ++u) {
        int ci = u * 256 + tid;
        async16(E_sw + ci * 8, kc_lds + ci * 8);
    }

    // ---- stage t, w1a1, ex rows ----
    #pragma unroll
    for (int u = 0; u < 4; ++u) t_lds[u * 256 + tid] = tarr[u * 256 + tid];
    if (tid < FDIM) w1a1_lds[tid] = w1a1[tid];
    const int r0 = tid >> 3;
    const int fc = (tid & 7) * 16;
    float exv[16];
    {
        const float* src = ex_h + (size_t)(R0 + r0) * FDIM + fc;
        #pragma unroll
        for (int c = 0; c < 4; ++c) {
            float4 v = *(const float4*)(src + c * 4);
            exv[c * 4 + 0] = v.x; exv[c * 4 + 1] = v.y;
            exv[c * 4 + 2] = v.z; exv[c * 4 + 3] = v.w;
        }
        unsigned pk[8];
        #pragma unroll
        for (int i = 0; i < 8; ++i)
            pk[i] = (unsigned)f2bf(exv[2 * i]) | ((unsigned)f2bf(exv[2 * i + 1]) << 16);
        *(uint4*)(exw_lds + r0 * EXS + fc)     = make_uint4(pk[0], pk[1], pk[2], pk[3]);
        *(uint4*)(exw_lds + r0 * EXS + fc + 8) = make_uint4(pk[4], pk[5], pk[6], pk[7]);
    }
    __syncthreads();   // drains E async + LDS writes

    // ---- Tmax + s partials ----
    {
        float mx = fmaxf(fmaxf(t_lds[tid], t_lds[256 + tid]),
                         fmaxf(t_lds[512 + tid], t_lds[768 + tid]));
        scrB[tid] = mx;
        float p = 0.f;
        #pragma unroll
        for (int i = 0; i < 16; ++i) p += exv[i] * w1a1_lds[fc + i];
        scrA[tid] = p;
    }
    __syncthreads();
    if (tid < 64)
        scrB[tid] = fmaxf(fmaxf(scrB[tid], scrB[tid + 64]),
                          fmaxf(scrB[tid + 128], scrB[tid + 192]));
    __syncthreads();
    if (tid < BR) {
        float Tm = scrB[0];
        #pragma unroll 8
        for (int i = 1; i < 64; ++i) Tm = fmaxf(Tm, scrB[i]);
        float s = 0.f;
        #pragma unroll
        for (int g = 0; g < 8; ++g) s += scrA[tid * 8 + g];
        s_lds[tid] = s;
        float x = s + Tm;
        m_lds[tid] = (x >= 0.f) ? x : LEAKY_S * x;
    }
    __syncthreads();   // REQUIRED: publish s_lds/m_lds to all waves (R3 NaN was this race)

    // ---- Eh = ex @ E via MFMA (E already in kc_lds, swizzled) ----
    floatx4 eh_acc[2][2], att_acc[2][2];
    #pragma unroll
    for (int mg = 0; mg < 2; ++mg)
        #pragma unroll
        for (int h = 0; h < 2; ++h) {
            eh_acc[mg][h]  = (floatx4){0.f, 0.f, 0.f, 0.f};
            att_acc[mg][h] = (floatx4){0.f, 0.f, 0.f, 0.f};
        }
    #pragma unroll
    for (int kk = 0; kk < 4; ++kk) {
        short8 a0 = *(const short8*)(exw_lds + l15 * EXS + kk * 32 + quad * 8);
        short8 a1 = *(const short8*)(exw_lds + (16 + l15) * EXS + kk * 32 + quad * 8);
        #pragma unroll
        for (int h = 0; h < 2; ++h) {
            const int n = (h * 4 + wid) * 16 + l15;
            const int cp = (kk * 4 + quad) ^ l15;
            short8 bf = *(const short8*)(kc_lds + n * TJ + cp * 8);
            eh_acc[0][h] = __builtin_amdgcn_mfma_f32_16x16x32_bf16(a0, bf, eh_acc[0][h], 0, 0, 0);
            eh_acc[1][h] = __builtin_amdgcn_mfma_f32_16x16x32_bf16(a1, bf, eh_acc[1][h], 0, 0, 0);
        }
    }

    // ---- main j loop: 8 tiles of 128 ----
    const int r_w = tid >> 3;          // w-gen row
    const int jg  = tid & 7;           // 16-j chunk within tile
    const float sr = s_lds[r_w];
    const float mr = m_lds[r_w];
    float denom_part = 0.f;
    const int* aptr = adj + (size_t)(R0 + r_w) * N_KCC + jg * 16;
    int4 cur0 = *(const int4*)(aptr + 0);
    int4 cur1 = *(const int4*)(aptr + 4);
    int4 cur2 = *(const int4*)(aptr + 8);
    int4 cur3 = *(const int4*)(aptr + 12);

    for (int jt = 0; jt < N_KCC / TJ; ++jt) {
        const int j0 = jt * TJ;
        __syncthreads();   // barrier A: prev MFMA (and Eh at jt=0) LDS reads done
        // async stage kc tile (32 KB, pre-swizzled contiguous)
        {
            const ushort_t* gsrc = kc_sw + (size_t)jt * (FDIM * TJ);
            #pragma unroll
            for (int u = 0; u < 8; ++u) {
                int ci = u * 256 + tid;
                async16(gsrc + ci * 8, kc_lds + ci * 8);
            }
        }
        // w generation: 16 j per thread, fp32 math, bf16 pack
        {
            const int jb = j0 + jg * 16;
            int av[16] = {cur0.x, cur0.y, cur0.z, cur0.w, cur1.x, cur1.y, cur1.z, cur1.w,
                          cur2.x, cur2.y, cur2.z, cur2.w, cur3.x, cur3.y, cur3.z, cur3.w};
            float wv[16];
            #pragma unroll
            for (int c = 0; c < 4; ++c) {
                float4 t4 = *(const float4*)(t_lds + jb + c * 4);
                float tv[4] = {t4.x, t4.y, t4.z, t4.w};
                #pragma unroll
                for (int e = 0; e < 4; ++e) {
                    float x = sr + tv[e];
                    x = fmaxf(x, LEAKY_S * x);           // leaky_relu
                    float w = __expf(x - mr);
                    w = (av[c * 4 + e] > 0) ? w : 0.f;
                    denom_part += w;
                    wv[c * 4 + e] = w;
                }
            }
            unsigned pk[8];
            #pragma unroll
            for (int i = 0; i < 8; ++i) {
                unsigned ua = __float_as_uint(wv[2 * i + 0]) + 0x8000u;
                unsigned ub = __float_as_uint(wv[2 * i + 1]) + 0x8000u;
                pk[i] = __builtin_amdgcn_perm(ub, ua, 0x07060302);  // bf16 pair
            }
            *(uint4*)(exw_lds + r_w * EXS + jg * 16)     = make_uint4(pk[0], pk[1], pk[2], pk[3]);
            *(uint4*)(exw_lds + r_w * EXS + jg * 16 + 8) = make_uint4(pk[4], pk[5], pk[6], pk[7]);
        }
        __syncthreads();   // barrier B: drains async kc + w writes
        // adj prefetch for next tile (in flight during MFMA section)
        {
            int jn = (jt + 1 < N_KCC / TJ) ? (jt + 1) * TJ : jt * TJ;
            cur0 = *(const int4*)(aptr + jn + 0);
            cur1 = *(const int4*)(aptr + jn + 4);
            cur2 = *(const int4*)(aptr + jn + 8);
            cur3 = *(const int4*)(aptr + jn + 12);
        }
        // MFMA: att += w[32 x 128] @ kcWh_tile[128 x 128]
        #pragma unroll
        for (int kk = 0; kk < 4; ++kk) {
            short8 a0 = *(const short8*)(exw_lds + l15 * EXS + kk * 32 + quad * 8);
            short8 a1 = *(const short8*)(exw_lds + (16 + l15) * EXS + kk * 32 + quad * 8);
            #pragma unroll
            for (int h = 0; h < 2; ++h) {
                const int f = (h * 4 + wid) * 16 + l15;
                const int cp = (kk * 4 + quad) ^ l15;
                short8 bf = *(const short8*)(kc_lds + f * TJ + cp * 8);
                att_acc[0][h] = __builtin_amdgcn_mfma_f32_16x16x32_bf16(a0, bf, att_acc[0][h], 0, 0, 0);
                att_acc[1][h] = __builtin_amdgcn_mfma_f32_16x16x32_bf16(a1, bf, att_acc[1][h], 0, 0, 0);
            }
        }
    }

    // ---- denominator reduce ----
    __syncthreads();
    scrA[tid] = denom_part;
    __syncthreads();
    if (tid < BR) {
        float d = 0.f;
        #pragma unroll
        for (int g = 0; g < 8; ++g) d += scrA[tid * 8 + g];
        denom_lds[tid] = (d > 0.f) ? d : 1.f;
    }
    __syncthreads();

    // ---- epilogue: normalize * Eh, elu, store (C-layout: col=l15, row=quad*4+reg) ----
    #pragma unroll
    for (int mg = 0; mg < 2; ++mg) {
        float rd[4];
        #pragma unroll
        for (int reg = 0; reg < 4; ++reg)
            rd[reg] = 1.f / denom_lds[mg * 16 + quad * 4 + reg];
        #pragma unroll
        for (int h = 0; h < 2; ++h) {
            const int col = (h * 4 + wid) * 16 + l15;
            #pragma unroll
            for (int reg = 0; reg < 4; ++reg) {
                const int rl = mg * 16 + quad * 4 + reg;
                float v = att_acc[mg][h][reg] * rd[reg] * eh_acc[mg][h][reg];
                out[(size_t)(R0 + rl) * FDIM + col] = (v > 0.f) ? v : expm1f(v);
            }
        }
    }
}

extern "C" void kernel_launch(void* const* d_in, const int* in_sizes, int n_in,
                              void* d_out, int out_size, void* d_ws, size_t ws_size,
                              hipStream_t stream)
{
    const float* ex_h = (const float*)d_in[0];
    const float* kc_h = (const float*)d_in[1];
    const int*   adj  = (const int*)d_in[2];
    const float* W1   = (const float*)d_in[3];
    const float* E    = (const float*)d_in[4];
    const float* a    = (const float*)d_in[5];
    float* outp = (float*)d_out;
    float* ws   = (float*)d_ws;

    gat_prep<<<37, 256, 0, stream>>>(kc_h, W1, E, a, ws);
    gat_main<<<N_EXC / BR, 256, 0, stream>>>(ex_h, adj, ws, outp);
}